// Round 9
// baseline (96.625 us; speedup 1.0000x reference)
//
#include <hip/hip_runtime.h>

#define B 8
#define C 4
#define H 384
#define W 384
#define HW (H * W)
#define CHW (C * H * W)
#define NTOT (B * CHW)        // 4,718,592
#define BIG2 589824           // 768^2, reference's BIG cap squared
#define TPI 144               // tiles per image (12x12 of 32x32)
#define NBLK (B * TPI)        // 1152
#define LOG2E 1.44269504088896340736f

// Full-width 64-bit scan (slow/rare paths only). min over set bits p of
// (p - lx)^2 ; 999 sentinel if empty side. lx in [16,48).
__device__ __forceinline__ int nearest2(unsigned long long m, int lx, int shl) {
    unsigned long long right = m >> lx;
    int dR = right ? (int)__builtin_ctzll(right) : 999;
    unsigned long long leftb = m << shl;            // shl = 63 - lx
    int dL = leftb ? (int)__builtin_clzll(leftb) : 999;
    int d = min(dR, dL);
    return d * d;
}

// Windowed 32-bit scan, sentinel-bit form (no cmp/cndmask guards).
// right: bit0 = own pixel, bit k = dx=+k; left: bit31 = own, bit31-k = dx=-k.
// Sentinel bit forces nonzero input -> plain v_ffbl/v_ffbh; empty side reads
// as d=31 -> >= 961, which the rare path promotes to BIG2 before the exact
// ring fallback (conflated far pixels are rediscovered there exactly).
__device__ __forceinline__ int scan32f(unsigned int right, unsigned int left, int add) {
    int dR = __builtin_ctz(right | 0x80000000u);
    int dL = __builtin_clz(left | 1u);
    int d = min(dR, dL);
    return d * d + add;
}

// Exact Chebyshev-ring global-memory scan (essentially never taken).
__device__ __attribute__((noinline))
int ring_fallback(const int* __restrict__ tg, int xa, int ya, int c, int best) {
    for (int d = 17; d * d < best; ++d) {
        int xlo = xa - d, xhi = xa + d, ylo = ya - d, yhi = ya + d;
        for (int xx = max(xlo, 0); xx <= min(xhi, W - 1); ++xx) {
            int ddx = xx - xa;
            int bb = ddx * ddx + d * d;
            if (bb < best) {
                if (ylo >= 0 && tg[ylo * W + xx] == c) best = bb;
                if (yhi < H && tg[yhi * W + xx] == c) best = min(best, bb);
            }
        }
        for (int yy = max(ylo + 1, 0); yy <= min(yhi - 1, H - 1); ++yy) {
            int ddy = yy - ya;
            int bb = ddy * ddy + d * d;
            if (bb < best) {
                if (xlo >= 0 && tg[yy * W + xlo] == c) best = bb;
                if (xhi < W && tg[yy * W + xhi] == c) best = min(best, bb);
            }
        }
    }
    return best;
}

// 32x32 tile per block, 512 threads, 2 px/thread (R6 structure, best
// measured). Staging is IN-KERNEL ballot (8 iterations, one row per wave
// per iter) — drops the build_masks launch + its gap; rowsm content is
// bit-identical to the funnel/build version. Hot loop: windowed
// sentinel-bit scans. Finalize stays a separate kernel (per-block
// device-scope fences/atomics measured +19 us at this block count, R7).
__global__ __launch_bounds__(512)
void dist_loss_kernel(const float* __restrict__ outputs,
                      const int* __restrict__ targets,
                      float* __restrict__ parts) {
    __shared__ unsigned long long rowsm[64][4];   // window masks (y halo 16)
    __shared__ unsigned long long big[32 * 18];   // [y][c][lvl0..3], 144B/row pad
    __shared__ float sred[8][9];

    int bid = blockIdx.x;
    int bx = bid % 12, by = (bid / 12) % 12, b = bid / TPI;
    int x0 = bx * 32, y0 = by * 32;
    int tid = threadIdx.x, lane = tid & 63, wv = tid >> 6;
    const int* tg = targets + b * HW;

    // pixel-pair coords
    int x2 = (tid & 15) * 2;                // 0,2,...,30
    int y = tid >> 4;                       // 0..31
    int ya = y0 + y, ly = y + 16;

    // ---- issue outputs loads first: HBM latency hides under staging ----
    const float* ob = outputs + (size_t)b * CHW + (size_t)ya * W + (x0 + x2);
    float2 f0 = *(const float2*)ob;
    float2 f1 = *(const float2*)(ob + HW);
    float2 f2 = *(const float2*)(ob + 2 * HW);
    float2 f3 = *(const float2*)(ob + 3 * HW);

    // ---- stage 64 rows of class bitmasks via ballot: 8 iters, 1 row/wave ----
    bool edge = (bx == 0) | (bx == 11) | (by == 0) | (by == 11);
    if (!edge) {
        const int* tp = tg + (y0 - 16 + wv) * W + (x0 - 16 + lane);
        #pragma unroll
        for (int i = 0; i < 8; ++i) {
            int r = i * 8 + wv;
            int tv = tp[i * 8 * W];
            unsigned long long m0 = __ballot(tv == 0);
            unsigned long long m1 = __ballot(tv == 1);
            unsigned long long m2 = __ballot(tv == 2);
            unsigned long long m3 = __ballot(tv == 3);
            if (lane == 0) {
                rowsm[r][0] = m0; rowsm[r][1] = m1;
                rowsm[r][2] = m2; rowsm[r][3] = m3;
            }
        }
    } else {
        for (int i = 0; i < 8; ++i) {
            int r = i * 8 + wv;
            int yr = y0 - 16 + r, xr = x0 - 16 + lane;
            bool valid = (yr >= 0) & (yr < H) & (xr >= 0) & (xr < W);
            int yc = min(max(yr, 0), H - 1), xc = min(max(xr, 0), W - 1);
            int tv = tg[yc * W + xc];
            unsigned long long m0 = __ballot(valid && tv == 0);
            unsigned long long m1 = __ballot(valid && tv == 1);
            unsigned long long m2 = __ballot(valid && tv == 2);
            unsigned long long m3 = __ballot(valid && tv == 3);
            if (lane == 0) {
                rowsm[r][0] = m0; rowsm[r][1] = m1;
                rowsm[r][2] = m2; rowsm[r][3] = m3;
            }
        }
    }
    __syncthreads();

    // ---- pre-OR +-dy pairs: exactly one u64 per thread ----
    {
        int yy = tid >> 4, c = (tid >> 2) & 3, lvl = tid & 3;
        unsigned long long v = (lvl == 0)
            ? rowsm[16 + yy][c]
            : (rowsm[16 + yy - lvl][c] | rowsm[16 + yy + lvl][c]);
        big[yy * 18 + c * 4 + lvl] = v;
    }
    __syncthreads();

    float red[9];
    #pragma unroll
    for (int j = 0; j < 9; ++j) red[j] = 0.0f;

    // softmax probabilities for the 2 pixels
    float pr[4][2];                         // [class][pixel]
    {
        const float* fc0 = (const float*)&f0;
        const float* fc1 = (const float*)&f1;
        const float* fc2 = (const float*)&f2;
        const float* fc3 = (const float*)&f3;
        #pragma unroll
        for (int p = 0; p < 2; ++p) {
            float e0 = exp2f(fc0[p] * LOG2E);
            float e1 = exp2f(fc1[p] * LOG2E);
            float e2 = exp2f(fc2[p] * LOG2E);
            float e3 = exp2f(fc3[p] * LOG2E);
            float inv = 1.0f / (e0 + e1 + e2 + e3);
            pr[0][p] = e0 * inv; pr[1][p] = e1 * inv;
            pr[2][p] = e2 * inv; pr[3][p] = e3 * inv;
        }
    }

    #pragma unroll
    for (int c = 0; c < 4; ++c) {
        const ulonglong2* pp = (const ulonglong2*)&big[y * 18 + c * 4];
        ulonglong2 va = pp[0], vb = pp[1];
        unsigned long long r0 = va.x >> x2;     // dy = 0   (bit 16+p = pixel p)
        unsigned long long r1 = va.y >> x2;     // |dy| = 1
        unsigned long long r2 = vb.x >> x2;     // |dy| = 2
        unsigned long long r3 = vb.y >> x2;     // |dy| = 3
        unsigned int l0 = (unsigned int)r0, l1 = (unsigned int)r1;
        unsigned int l2 = (unsigned int)r2, l3 = (unsigned int)r3;
        #pragma unroll
        for (int p = 0; p < 2; ++p) {
            unsigned int w0r = (unsigned int)(r0 >> (16 + p));
            unsigned int w1r = (unsigned int)(r1 >> (16 + p));
            unsigned int w2r = (unsigned int)(r2 >> (16 + p));
            unsigned int w3r = (unsigned int)(r3 >> (16 + p));
            unsigned int w0l = l0 << (15 - p);
            unsigned int w1l = l1 << (15 - p);
            unsigned int w2l = l2 << (15 - p);
            unsigned int w3l = l3 << (15 - p);
            int best = scan32f(w0r, w0l, 0);
            best = min(best, scan32f(w1r, w1l, 1));
            best = min(best, scan32f(w2r, w2l, 4));
            best = min(best, scan32f(w3r, w3l, 9));
            if (best > 16) {                    // rare: exact extension
                int lx = 16 + x2 + p, shl = 63 - lx;
                for (int dy = 4; dy <= 16 && dy * dy < best; ++dy) {
                    unsigned long long mm = rowsm[ly + dy][c] | rowsm[ly - dy][c];
                    if (mm) best = min(best, dy * dy + nearest2(mm, lx, shl));
                }
                if (best > 289) {
                    // promote sentinel/conflated values (>= 961) to the BIG
                    // cap; ring is then exact (rediscovers any far pixel,
                    // returns BIG2 = 768^2 for absent classes = ref BIG).
                    if (best >= 961) best = BIG2;
                    best = ring_fallback(tg, x0 + x2 + p, ya, c, best);
                }
            }
            float dt = sqrtf((float)best);      // exact int < 2^24
            red[0] += pr[c][p] * dt;            // target class: dt==0
            if (w0r & 1u) red[1 + c] += pr[c][p];   // T contribution
            red[5 + c] = fmaxf(red[5 + c], dt); // slice max candidate
        }
    }

    // ---- block reduce: red[0..4] sum, red[5..8] max ----
    #pragma unroll
    for (int off = 32; off > 0; off >>= 1) {
        #pragma unroll
        for (int j = 0; j < 5; ++j) red[j] += __shfl_down(red[j], off);
        #pragma unroll
        for (int j = 5; j < 9; ++j) red[j] = fmaxf(red[j], __shfl_down(red[j], off));
    }
    if (lane == 0) {
        #pragma unroll
        for (int j = 0; j < 9; ++j) sred[wv][j] = red[j];
    }
    __syncthreads();

    // ---- cross-wave reduce by wave 0 (lanes 0..7 hold one wave each) ----
    if (wv == 0) {
        float v[9];
        #pragma unroll
        for (int j = 0; j < 9; ++j) v[j] = (lane < 8) ? sred[lane][j] : 0.0f;
        #pragma unroll
        for (int off = 4; off > 0; off >>= 1) {
            #pragma unroll
            for (int j = 0; j < 5; ++j) v[j] += __shfl_down(v[j], off);
            #pragma unroll
            for (int j = 5; j < 9; ++j) v[j] = fmaxf(v[j], __shfl_down(v[j], off));
        }
        if (lane == 0) {
            // SoA: plane j contiguous over blocks -> coalesced finalize reads
            #pragma unroll
            for (int j = 0; j < 9; ++j) parts[j * NBLK + bid] = v[j];
        }
    }
}

// Single block: reduce 1152 block partials (SoA planes) -> scalar loss.
__global__ __launch_bounds__(256)
void finalize(const float* __restrict__ parts, float* __restrict__ out) {
    __shared__ double asum[4];
    __shared__ double Tsh[32];
    __shared__ float Msh[32];
    int tid = threadIdx.x, lane = tid & 63, wv = tid >> 6;

    double a = 0.0;
    for (int i = tid; i < NBLK; i += 256) a += (double)parts[i];   // plane 0
    #pragma unroll
    for (int off = 32; off > 0; off >>= 1) a += __shfl_down(a, off);
    if (lane == 0) asum[wv] = a;

    for (int k = 0; k < 8; ++k) {
        int s = wv * 8 + k;
        int bb = s >> 2, cc = s & 3;
        double ts = 0.0;
        float ms = 0.0f;
        for (int i = lane; i < TPI; i += 64) {
            int blk = bb * TPI + i;
            ts += (double)parts[(1 + cc) * NBLK + blk];     // coalesced
            ms = fmaxf(ms, parts[(5 + cc) * NBLK + blk]);   // coalesced
        }
        #pragma unroll
        for (int off = 32; off > 0; off >>= 1) {
            ts += __shfl_down(ts, off);
            ms = fmaxf(ms, __shfl_down(ms, off));
        }
        if (lane == 0) { Tsh[s] = ts; Msh[s] = ms; }
    }
    __syncthreads();
    if (tid == 0) {
        double A = asum[0] + asum[1] + asum[2] + asum[3];
        double st = 0.0;
        for (int s = 0; s < 32; ++s) st += (double)Msh[s] * Tsh[s];
        out[0] = (float)((A - st) / ((double)C * (double)NTOT));
    }
}

extern "C" void kernel_launch(void* const* d_in, const int* in_sizes, int n_in,
                              void* d_out, int out_size, void* d_ws, size_t ws_size,
                              hipStream_t stream) {
    const float* outputs = (const float*)d_in[0];
    const int* targets = (const int*)d_in[1];
    float* out = (float*)d_out;
    float* parts = (float*)d_ws;   // 9 planes x NBLK floats = 41,472 B (SoA)

    dist_loss_kernel<<<NBLK, 512, 0, stream>>>(outputs, targets, parts);
    finalize<<<1, 256, 0, stream>>>(parts, out);
}

// Round 10
// 91.777 us; speedup vs baseline: 1.0528x; 1.0528x over previous
//
#include <hip/hip_runtime.h>

#define B 8
#define C 4
#define H 384
#define W 384
#define HW (H * W)
#define CHW (C * H * W)
#define NTOT (B * CHW)        // 4,718,592
#define BIG2 589824           // 768^2, reference's BIG cap squared
#define TPI 144               // tiles per image (12x12 of 32x32)
#define NBLK (B * TPI)        // 1152
#define NSEG (B * H * 6)      // 18432 row-segments of 64 px
#define LOG2E 1.44269504088896340736f

// Full-width 64-bit scan (slow/rare paths only). min over set bits p of
// (p - lx)^2 ; 999 sentinel if empty side. lx in [16,48).
__device__ __forceinline__ int nearest2(unsigned long long m, int lx, int shl) {
    unsigned long long right = m >> lx;
    int dR = right ? (int)__builtin_ctzll(right) : 999;
    unsigned long long leftb = m << shl;            // shl = 63 - lx
    int dL = leftb ? (int)__builtin_clzll(leftb) : 999;
    int d = min(dR, dL);
    return d * d;
}

// Windowed 32-bit scan, sentinel-bit form (no cmp/cndmask guards).
// right: bit0 = own pixel, bit k = dx=+k; left: bit31 = own, bit31-k = dx=-k.
// Sentinel bit forces nonzero input -> plain v_ffbl/v_ffbh; empty side reads
// as d=31 -> >= 961, which the rare path promotes to BIG2 before the exact
// ring fallback (conflated far pixels are rediscovered there exactly).
__device__ __forceinline__ int scan32f(unsigned int right, unsigned int left, int add) {
    int dR = __builtin_ctz(right | 0x80000000u);
    int dL = __builtin_clz(left | 1u);
    int d = min(dR, dL);
    return d * d + add;
}

// Exact Chebyshev-ring global-memory scan (essentially never taken).
__device__ __attribute__((noinline))
int ring_fallback(const int* __restrict__ tg, int xa, int ya, int c, int best) {
    for (int d = 17; d * d < best; ++d) {
        int xlo = xa - d, xhi = xa + d, ylo = ya - d, yhi = ya + d;
        for (int xx = max(xlo, 0); xx <= min(xhi, W - 1); ++xx) {
            int ddx = xx - xa;
            int bb = ddx * ddx + d * d;
            if (bb < best) {
                if (ylo >= 0 && tg[ylo * W + xx] == c) best = bb;
                if (yhi < H && tg[yhi * W + xx] == c) best = min(best, bb);
            }
        }
        for (int yy = max(ylo + 1, 0); yy <= min(yhi - 1, H - 1); ++yy) {
            int ddy = yy - ya;
            int bb = ddy * ddy + d * d;
            if (bb < best) {
                if (xlo >= 0 && tg[yy * W + xlo] == c) best = bb;
                if (xhi < W && tg[yy * W + xhi] == c) best = min(best, bb);
            }
        }
    }
    return best;
}

// Build per-class row bitmasks once: masks[(b*H+y)*24 + c*6 + word].
// One wave per 64-px row segment; 4 ballots; lane0 writes 4 u64.
// A/B history (10 rounds): in-kernel ballot staging instead of this table
// costs +0.8 us (256t) to +3.4 us (512t); keep the separate kernel.
__global__ __launch_bounds__(256)
void build_masks(const int* __restrict__ targets,
                 unsigned long long* __restrict__ masks) {
    int wv = threadIdx.x >> 6, lane = threadIdx.x & 63;
    int seg = blockIdx.x * 4 + wv;
    if (seg >= NSEG) return;
    int wd = seg % 6, rem = seg / 6;          // rem = b*H + y
    int tv = targets[rem * W + wd * 64 + lane];
    unsigned long long m0 = __ballot(tv == 0);
    unsigned long long m1 = __ballot(tv == 1);
    unsigned long long m2 = __ballot(tv == 2);
    unsigned long long m3 = __ballot(tv == 3);
    if (lane == 0) {
        unsigned long long* dst = masks + (size_t)rem * 24 + wd;
        dst[0]  = m0;
        dst[6]  = m1;
        dst[12] = m2;
        dst[18] = m3;
    }
}

// 32x32 tile per block, 512 threads, 2 px/thread — best measured config
// (93.18 / 93.23 us, absmax 0.0; champion of 10 structural variants).
// Staging: threads 0..255 funnel-shift one (row, class) 64-bit window from
// the precomputed global masks (one iteration, two L2-hit u64 loads each).
// Hot loop: windowed sentinel-bit scans. Finalize is a SEPARATE kernel:
// per-block device-scope fences/atomics measured +17-19 us at this block
// count (R7) — kernel boundaries beat manufactured grid-wide ordering.
__global__ __launch_bounds__(512)
void dist_loss_kernel(const float* __restrict__ outputs,
                      const int* __restrict__ targets,
                      const unsigned long long* __restrict__ masks,
                      float* __restrict__ parts) {
    __shared__ unsigned long long rowsm[64][4];   // window masks (y halo 16)
    __shared__ unsigned long long big[32 * 18];   // [y][c][lvl0..3], 144B/row pad
    __shared__ float sred[8][9];

    int bid = blockIdx.x;
    int bx = bid % 12, by = (bid / 12) % 12, b = bid / TPI;
    int x0 = bx * 32, y0 = by * 32;
    int tid = threadIdx.x, lane = tid & 63, wv = tid >> 6;
    const int* tg = targets + b * HW;

    // pixel-pair coords
    int x2 = (tid & 15) * 2;                // 0,2,...,30
    int y = tid >> 4;                       // 0..31
    int ya = y0 + y, ly = y + 16;

    // ---- issue outputs loads first: HBM latency hides under staging ----
    const float* ob = outputs + (size_t)b * CHW + (size_t)ya * W + (x0 + x2);
    float2 f0 = *(const float2*)ob;
    float2 f1 = *(const float2*)(ob + HW);
    float2 f2 = *(const float2*)(ob + 2 * HW);
    float2 f3 = *(const float2*)(ob + 3 * HW);

    // ---- stage 64 rows x 4 classes of 64-bit windows: threads 0..255 ----
    if (tid < 256) {
        int r = tid >> 2, cc = tid & 3;
        int yaS = y0 - 16 + r;
        unsigned long long wmask = 0ull;
        if (yaS >= 0 && yaS < H) {
            const unsigned long long* mrow =
                masks + ((size_t)(b * H + yaS)) * 24 + cc * 6;
            int bitpos = x0 - 16;                 // window start bit in image
            int iw = bitpos >> 6, sh = bitpos & 63;   // sh in {16,48}
            unsigned long long lo = (iw >= 0) ? mrow[iw] : 0ull;
            unsigned long long hi = (iw + 1 < 6) ? mrow[iw + 1] : 0ull;
            wmask = (lo >> sh) | (hi << (64 - sh));
        }
        rowsm[r][cc] = wmask;
    }
    __syncthreads();

    // ---- pre-OR +-dy pairs: exactly one u64 per thread ----
    {
        int yy = tid >> 4, c = (tid >> 2) & 3, lvl = tid & 3;
        unsigned long long v = (lvl == 0)
            ? rowsm[16 + yy][c]
            : (rowsm[16 + yy - lvl][c] | rowsm[16 + yy + lvl][c]);
        big[yy * 18 + c * 4 + lvl] = v;
    }
    __syncthreads();

    float red[9];
    #pragma unroll
    for (int j = 0; j < 9; ++j) red[j] = 0.0f;

    // softmax probabilities for the 2 pixels
    float pr[4][2];                         // [class][pixel]
    {
        const float* fc0 = (const float*)&f0;
        const float* fc1 = (const float*)&f1;
        const float* fc2 = (const float*)&f2;
        const float* fc3 = (const float*)&f3;
        #pragma unroll
        for (int p = 0; p < 2; ++p) {
            float e0 = exp2f(fc0[p] * LOG2E);
            float e1 = exp2f(fc1[p] * LOG2E);
            float e2 = exp2f(fc2[p] * LOG2E);
            float e3 = exp2f(fc3[p] * LOG2E);
            float inv = 1.0f / (e0 + e1 + e2 + e3);
            pr[0][p] = e0 * inv; pr[1][p] = e1 * inv;
            pr[2][p] = e2 * inv; pr[3][p] = e3 * inv;
        }
    }

    #pragma unroll
    for (int c = 0; c < 4; ++c) {
        const ulonglong2* pp = (const ulonglong2*)&big[y * 18 + c * 4];
        ulonglong2 va = pp[0], vb = pp[1];
        unsigned long long r0 = va.x >> x2;     // dy = 0   (bit 16+p = pixel p)
        unsigned long long r1 = va.y >> x2;     // |dy| = 1
        unsigned long long r2 = vb.x >> x2;     // |dy| = 2
        unsigned long long r3 = vb.y >> x2;     // |dy| = 3
        unsigned int l0 = (unsigned int)r0, l1 = (unsigned int)r1;
        unsigned int l2 = (unsigned int)r2, l3 = (unsigned int)r3;
        #pragma unroll
        for (int p = 0; p < 2; ++p) {
            unsigned int w0r = (unsigned int)(r0 >> (16 + p));
            unsigned int w1r = (unsigned int)(r1 >> (16 + p));
            unsigned int w2r = (unsigned int)(r2 >> (16 + p));
            unsigned int w3r = (unsigned int)(r3 >> (16 + p));
            unsigned int w0l = l0 << (15 - p);
            unsigned int w1l = l1 << (15 - p);
            unsigned int w2l = l2 << (15 - p);
            unsigned int w3l = l3 << (15 - p);
            int best = scan32f(w0r, w0l, 0);
            best = min(best, scan32f(w1r, w1l, 1));
            best = min(best, scan32f(w2r, w2l, 4));
            best = min(best, scan32f(w3r, w3l, 9));
            if (best > 16) {                    // rare: exact extension
                int lx = 16 + x2 + p, shl = 63 - lx;
                for (int dy = 4; dy <= 16 && dy * dy < best; ++dy) {
                    unsigned long long mm = rowsm[ly + dy][c] | rowsm[ly - dy][c];
                    if (mm) best = min(best, dy * dy + nearest2(mm, lx, shl));
                }
                if (best > 289) {
                    // promote sentinel/conflated values (>= 961) to the BIG
                    // cap; ring is then exact (rediscovers any far pixel,
                    // returns BIG2 = 768^2 for absent classes = ref BIG).
                    if (best >= 961) best = BIG2;
                    best = ring_fallback(tg, x0 + x2 + p, ya, c, best);
                }
            }
            float dt = sqrtf((float)best);      // exact int < 2^24
            red[0] += pr[c][p] * dt;            // target class: dt==0
            if (w0r & 1u) red[1 + c] += pr[c][p];   // T contribution
            red[5 + c] = fmaxf(red[5 + c], dt); // slice max candidate
        }
    }

    // ---- block reduce: red[0..4] sum, red[5..8] max ----
    #pragma unroll
    for (int off = 32; off > 0; off >>= 1) {
        #pragma unroll
        for (int j = 0; j < 5; ++j) red[j] += __shfl_down(red[j], off);
        #pragma unroll
        for (int j = 5; j < 9; ++j) red[j] = fmaxf(red[j], __shfl_down(red[j], off));
    }
    if (lane == 0) {
        #pragma unroll
        for (int j = 0; j < 9; ++j) sred[wv][j] = red[j];
    }
    __syncthreads();

    // ---- cross-wave reduce by wave 0 (lanes 0..7 hold one wave each) ----
    if (wv == 0) {
        float v[9];
        #pragma unroll
        for (int j = 0; j < 9; ++j) v[j] = (lane < 8) ? sred[lane][j] : 0.0f;
        #pragma unroll
        for (int off = 4; off > 0; off >>= 1) {
            #pragma unroll
            for (int j = 0; j < 5; ++j) v[j] += __shfl_down(v[j], off);
            #pragma unroll
            for (int j = 5; j < 9; ++j) v[j] = fmaxf(v[j], __shfl_down(v[j], off));
        }
        if (lane == 0) {
            // SoA: plane j contiguous over blocks -> coalesced finalize reads
            #pragma unroll
            for (int j = 0; j < 9; ++j) parts[j * NBLK + bid] = v[j];
        }
    }
}

// Single block: reduce 1152 block partials (SoA planes) -> scalar loss.
__global__ __launch_bounds__(256)
void finalize(const float* __restrict__ parts, float* __restrict__ out) {
    __shared__ double asum[4];
    __shared__ double Tsh[32];
    __shared__ float Msh[32];
    int tid = threadIdx.x, lane = tid & 63, wv = tid >> 6;

    double a = 0.0;
    for (int i = tid; i < NBLK; i += 256) a += (double)parts[i];   // plane 0
    #pragma unroll
    for (int off = 32; off > 0; off >>= 1) a += __shfl_down(a, off);
    if (lane == 0) asum[wv] = a;

    for (int k = 0; k < 8; ++k) {
        int s = wv * 8 + k;
        int bb = s >> 2, cc = s & 3;
        double ts = 0.0;
        float ms = 0.0f;
        for (int i = lane; i < TPI; i += 64) {
            int blk = bb * TPI + i;
            ts += (double)parts[(1 + cc) * NBLK + blk];     // coalesced
            ms = fmaxf(ms, parts[(5 + cc) * NBLK + blk]);   // coalesced
        }
        #pragma unroll
        for (int off = 32; off > 0; off >>= 1) {
            ts += __shfl_down(ts, off);
            ms = fmaxf(ms, __shfl_down(ms, off));
        }
        if (lane == 0) { Tsh[s] = ts; Msh[s] = ms; }
    }
    __syncthreads();
    if (tid == 0) {
        double A = asum[0] + asum[1] + asum[2] + asum[3];
        double st = 0.0;
        for (int s = 0; s < 32; ++s) st += (double)Msh[s] * Tsh[s];
        out[0] = (float)((A - st) / ((double)C * (double)NTOT));
    }
}

extern "C" void kernel_launch(void* const* d_in, const int* in_sizes, int n_in,
                              void* d_out, int out_size, void* d_ws, size_t ws_size,
                              hipStream_t stream) {
    const float* outputs = (const float*)d_in[0];
    const int* targets = (const int*)d_in[1];
    float* out = (float*)d_out;
    // workspace layout:
    float* parts = (float*)d_ws;                                   // 41,472 B
    unsigned long long* masks =
        (unsigned long long*)((char*)d_ws + 64 * 1024);            // 589,824 B

    build_masks<<<NSEG / 4, 256, 0, stream>>>(targets, masks);
    dist_loss_kernel<<<NBLK, 512, 0, stream>>>(outputs, targets, masks, parts);
    finalize<<<1, 256, 0, stream>>>(parts, out);
}